// Round 8
// baseline (665.056 us; speedup 1.0000x reference)
//
#include <hip/hip_runtime.h>
#include <cstdint>
#include <cstddef>

constexpr int F_IN  = 512;
constexpr int D_EMB = 128;
constexpr int D_HID = 64;
constexpr int N_CLS = 32;

typedef __attribute__((ext_vector_type(8))) short short8;
typedef __attribute__((ext_vector_type(4))) float floatx4;

__device__ inline unsigned short f2bf(float f) {
  union { float f; uint32_t u; } v; v.f = f;
  uint32_t r = v.u + 0x7FFF + ((v.u >> 16) & 1);   // round-to-nearest-even
  return (unsigned short)(r >> 16);
}

__device__ inline uint32_t pack2bf(float lo, float hi) {
  return ((uint32_t)f2bf(hi) << 16) | (uint32_t)f2bf(lo);
}

// ---- W1 -> fragment-linear bf16: Wt2[kc8][ct][ks][lane] of short8 ----------
__global__ __launch_bounds__(256) void wt_kernel(
    const float* __restrict__ W1, short8* __restrict__ Wt2)
{
  int idx = blockIdx.x * 256 + threadIdx.x;     // 0..8191
  int kc8 = idx >> 10, lin = idx & 1023;
  int ct = lin >> 7, rem = lin & 127, ks = rem >> 6, ln = rem & 63;
  int col = ct * 16 + (ln & 15);
  int k0 = kc8 * 64 + ks * 32 + (ln >> 4) * 8;
  short8 s;
#pragma unroll
  for (int j = 0; j < 8; ++j)
    s[j] = (short)f2bf(W1[(size_t)(k0 + j) * D_EMB + col]);
  Wt2[idx] = s;
}

// ---- fused lin1 + conv1-mm: P(bf16) = relu(X @ W1 + b1) @ Wc1 --------------
__global__ __launch_bounds__(256) void l1c1_kernel(
    const float* __restrict__ X, const short8* __restrict__ Wt2,
    const float* __restrict__ b1, const float* __restrict__ Wc1,
    unsigned short* __restrict__ P, int n)
{
  __shared__ __align__(16) char smem[50176];
  short8* Xs = (short8*)smem;                      // 8 KB   (phase 1)
  short8* Ws = (short8*)(smem + 8192);             // 16 KB  (phase 1)
  float (*Hs)[132] = (float(*)[132])smem;          // 33792B (phase 2, aliases)
  float (*Wc)[64]  = (float(*)[64])(smem + 33792); // 16 KB  (phase 2)

  const int t = threadIdx.x;
  const int wave = t >> 6, lane = t & 63;
  const int quad = lane >> 4, mrow = lane & 15;
  const int node0 = blockIdx.x * 64;
  const int cw = wave * 2;                         // col-tile base (2 per wave)

  // phase-2 Wc1 half-0 prefetch: issued now, consumed after the K-loop
  float4 wp[4];
#pragma unroll
  for (int i = 0; i < 4; ++i) wp[i] = ((const float4*)Wc1)[i * 256 + t];

  // X staging assignment: g = t + i*256 (i<2); row = g>>3, col8 = g&7
  const float* sp[2];
  int soff[2];
#pragma unroll
  for (int i = 0; i < 2; ++i) {
    int g = t + i * 256;
    int row = g >> 3, col8 = g & 7;
    soff[i] = row * 128 + ((col8 * 16) ^ ((row & 7) << 4));
    int gr = node0 + row; if (gr >= n) gr = n - 1;
    sp[i] = &X[(size_t)gr * F_IN + col8 * 8];
  }

  floatx4 acc[4][2];
#pragma unroll
  for (int i = 0; i < 4; ++i)
#pragma unroll
    for (int j = 0; j < 2; ++j) acc[i][j] = (floatx4){0.f, 0.f, 0.f, 0.f};

  float4 xrA[2][2], xrB[2][2];    // 2-deep X prefetch (tiles k, k+1)
  short8 wrA[4], wrB[4];          // 2-deep W prefetch

#pragma unroll
  for (int i = 0; i < 2; ++i) {   // prologue: tiles 0 and 1
    xrA[i][0] = *(const float4*)sp[i];
    xrA[i][1] = *(const float4*)(sp[i] + 4);
    xrB[i][0] = *(const float4*)(sp[i] + 64);
    xrB[i][1] = *(const float4*)(sp[i] + 68);
  }
#pragma unroll
  for (int i = 0; i < 4; ++i) {
    wrA[i] = Wt2[t + i * 256];
    wrB[i] = Wt2[1024 + t + i * 256];
  }

  auto substep = [&](float4 (&xr)[2][2], short8 (&wr)[4], int knext) {
    short8 s8[2];
#pragma unroll
    for (int i = 0; i < 2; ++i) {
      s8[i][0] = (short)f2bf(xr[i][0].x); s8[i][1] = (short)f2bf(xr[i][0].y);
      s8[i][2] = (short)f2bf(xr[i][0].z); s8[i][3] = (short)f2bf(xr[i][0].w);
      s8[i][4] = (short)f2bf(xr[i][1].x); s8[i][5] = (short)f2bf(xr[i][1].y);
      s8[i][6] = (short)f2bf(xr[i][1].z); s8[i][7] = (short)f2bf(xr[i][1].w);
    }
    __syncthreads();                      // WAR: prev tile's compute done
#pragma unroll
    for (int i = 0; i < 2; ++i)
      *(short8*)((char*)Xs + soff[i]) = s8[i];
#pragma unroll
    for (int i = 0; i < 4; ++i)
      Ws[t + i * 256] = wr[i];
    __syncthreads();                      // tile visible

    if (knext < 8) {                      // refill this buffer, 2 tiles ahead
#pragma unroll
      for (int i = 0; i < 2; ++i) {
        const float* p = sp[i] + knext * 64;
        xr[i][0] = *(const float4*)p;
        xr[i][1] = *(const float4*)(p + 4);
      }
#pragma unroll
      for (int i = 0; i < 4; ++i)
        wr[i] = Wt2[knext * 1024 + t + i * 256];
    }

#pragma unroll
    for (int ks = 0; ks < 2; ++ks) {
      short8 af[4], bf[2];
#pragma unroll
      for (int rt = 0; rt < 4; ++rt) {
        int row = rt * 16 + mrow;
        int byteoff = row * 128 + ((ks * 64 + quad * 16) ^ ((row & 7) << 4));
        af[rt] = *(const short8*)((const char*)Xs + byteoff);
      }
#pragma unroll
      for (int c = 0; c < 2; ++c)
        bf[c] = Ws[((cw + c) * 2 + ks) * 64 + lane];
#pragma unroll
      for (int rt = 0; rt < 4; ++rt)
#pragma unroll
        for (int c = 0; c < 2; ++c)
          acc[rt][c] = __builtin_amdgcn_mfma_f32_16x16x32_bf16(
              af[rt], bf[c], acc[rt][c], 0, 0, 0);
    }
  };

#pragma unroll 1
  for (int kc8 = 0; kc8 < 8; kc8 += 2) {
    substep(xrA, wrA, kc8 + 2);
    substep(xrB, wrB, kc8 + 3);
  }

  // ---------------- phase 2: P-tile = relu(H1-tile) @ Wc1 -------------------
  __syncthreads();                        // all Xs/Ws reads complete (alias!)
#pragma unroll
  for (int ct = 0; ct < 2; ++ct) {
    int col = (cw + ct) * 16 + mrow;
    float b = b1[col];
#pragma unroll
    for (int rt = 0; rt < 4; ++rt)
#pragma unroll
      for (int r = 0; r < 4; ++r)
        Hs[rt * 16 + quad * 4 + r][col] = fmaxf(acc[rt][ct][r] + b, 0.f);
  }
#pragma unroll
  for (int i = 0; i < 4; ++i)             // Wc1 half 0 into LDS
    ((float4*)&Wc[0][0])[i * 256 + t] = wp[i];
  __syncthreads();

#pragma unroll
  for (int i = 0; i < 4; ++i)             // prefetch Wc1 half 1
    wp[i] = ((const float4*)Wc1)[1024 + i * 256 + t];

  const int rg = t >> 4, cg = t & 15;
  float acc2[4][4];
#pragma unroll
  for (int i = 0; i < 4; ++i)
#pragma unroll
    for (int j = 0; j < 4; ++j) acc2[i][j] = 0.f;

#pragma unroll 8
  for (int k = 0; k < 64; ++k) {          // k = 0..63
    float a[4] = {Hs[rg*4+0][k], Hs[rg*4+1][k], Hs[rg*4+2][k], Hs[rg*4+3][k]};
    float4 b = *(const float4*)&Wc[k][cg * 4];
#pragma unroll
    for (int i = 0; i < 4; ++i) {
      acc2[i][0] += a[i]*b.x; acc2[i][1] += a[i]*b.y;
      acc2[i][2] += a[i]*b.z; acc2[i][3] += a[i]*b.w;
    }
  }
  __syncthreads();
#pragma unroll
  for (int i = 0; i < 4; ++i)             // Wc1 half 1 into LDS
    ((float4*)&Wc[0][0])[i * 256 + t] = wp[i];
  __syncthreads();

#pragma unroll 8
  for (int k = 0; k < 64; ++k) {          // k = 64..127
    float a[4] = {Hs[rg*4+0][64+k], Hs[rg*4+1][64+k],
                  Hs[rg*4+2][64+k], Hs[rg*4+3][64+k]};
    float4 b = *(const float4*)&Wc[k][cg * 4];
#pragma unroll
    for (int i = 0; i < 4; ++i) {
      acc2[i][0] += a[i]*b.x; acc2[i][1] += a[i]*b.y;
      acc2[i][2] += a[i]*b.z; acc2[i][3] += a[i]*b.w;
    }
  }
#pragma unroll
  for (int i = 0; i < 4; ++i) {
    int gn = node0 + rg * 4 + i;
    if (gn < n) {
      uint2 o;
      o.x = pack2bf(acc2[i][0], acc2[i][1]);
      o.y = pack2bf(acc2[i][2], acc2[i][3]);
      *(uint2*)&P[(size_t)gn * 64 + cg * 4] = o;
    }
  }
}

// ---- wide 4-group gather cores: lane = g*16+li (g in 0..3, li in 0..15) ----
// Lane covers cols [li*4, li*4+4); group g takes edges e === g (mod 4).
// bf16 row = 16 lanes x uint2 (8B/instr); fp32 row = 16 lanes x float4
// (16B/instr). 8-deep unroll = 32 edges in flight/wave. Two shfl_xor
// butterflies (16, 32) merge the 4 groups. Branchless tail: clamp to end-1
// (dup row = L1 hit), predicate adds (exact).
__device__ inline void gather4_bf(
    const unsigned short* __restrict__ P, const int* __restrict__ adj,
    int beg, int end, int g, int li, float c[4])
{
  c[0] = 0.f; c[1] = 0.f; c[2] = 0.f; c[3] = 0.f;
  if (end > beg) {
    int e1 = end - 1;
    for (int jj = beg + g; jj < end; jj += 32) {
#pragma unroll
      for (int k = 0; k < 8; ++k) {
        int e = jj + 4 * k;
        int ec = min(e, e1);
        int idx = adj[ec];
        uint2 u = *(const uint2*)&P[(size_t)idx * 64 + li * 4];
        bool p = e < end;
        c[0] += p ? __uint_as_float(u.x << 16) : 0.f;
        c[1] += p ? __uint_as_float(u.x & 0xFFFF0000u) : 0.f;
        c[2] += p ? __uint_as_float(u.y << 16) : 0.f;
        c[3] += p ? __uint_as_float(u.y & 0xFFFF0000u) : 0.f;
      }
    }
  }
#pragma unroll
  for (int i = 0; i < 4; ++i) {
    c[i] += __shfl_xor(c[i], 16, 64);
    c[i] += __shfl_xor(c[i], 32, 64);
  }
}

__device__ inline void gather4_f32(
    const float* __restrict__ P, const int* __restrict__ adj,
    int beg, int end, int g, int li, float c[4])
{
  c[0] = 0.f; c[1] = 0.f; c[2] = 0.f; c[3] = 0.f;
  if (end > beg) {
    int e1 = end - 1;
    for (int jj = beg + g; jj < end; jj += 32) {
#pragma unroll
      for (int k = 0; k < 8; ++k) {
        int e = jj + 4 * k;
        int ec = min(e, e1);
        int idx = adj[ec];
        float4 u = *(const float4*)&P[(size_t)idx * 64 + li * 4];
        bool p = e < end;
        c[0] += p ? u.x : 0.f;
        c[1] += p ? u.y : 0.f;
        c[2] += p ? u.z : 0.f;
        c[3] += p ? u.w : 0.f;
      }
    }
  }
#pragma unroll
  for (int i = 0; i < 4; ++i) {
    c[i] += __shfl_xor(c[i], 16, 64);
    c[i] += __shfl_xor(c[i], 32, 64);
  }
}

// ======= fused gather + pre + matmul: Out = pre(agg(P)) @ W =================
// INBF/OUTBF select bf16 or fp32 storage for P-in / P-out.
template<bool INBF, bool OUTBF>
__global__ __launch_bounds__(512) void gmm_kernel(
    const void* __restrict__ Pv, const int* __restrict__ offs,
    const int* __restrict__ adj, const int* __restrict__ deg,
    const float* __restrict__ bin, const float* __restrict__ W,
    void* __restrict__ Outv, int n)
{
  __shared__ float Hs[64][68];
  __shared__ float Ws[64][64];
  __shared__ int offss[65];
  const int t = threadIdx.x;
  const int wave = t >> 6, lane = t & 63;
  const int g = lane >> 4, li = lane & 15;
  const int node0 = blockIdx.x * 64;

#pragma unroll
  for (int i = 0; i < 2; ++i) {
    int lin = t + i * 512;
    ((float4*)&Ws[0][0])[lin] = ((const float4*)W)[lin];
  }
  if (t < 65) offss[t] = offs[min(node0 + t, n)];
  __syncthreads();

  const float4 bb = *(const float4*)&bin[li * 4];

#pragma unroll 1
  for (int nd = 0; nd < 8; ++nd) {
    int ln = wave * 8 + nd;
    int node = node0 + ln;
    if (node < n) {
      float c[4];
      if (INBF)
        gather4_bf((const unsigned short*)Pv, adj, offss[ln], offss[ln + 1],
                   g, li, c);
      else
        gather4_f32((const float*)Pv, adj, offss[ln], offss[ln + 1],
                    g, li, c);
      float rd = 1.f / fmaxf((float)deg[node], 1.f);
      float4 v = make_float4(fmaxf(c[0] * rd + bb.x, 0.f),
                             fmaxf(c[1] * rd + bb.y, 0.f),
                             fmaxf(c[2] * rd + bb.z, 0.f),
                             fmaxf(c[3] * rd + bb.w, 0.f));
      if (g == 0) *(float4*)&Hs[ln][li * 4] = v;
    } else if (g == 0) {
      *(float4*)&Hs[ln][li * 4] = make_float4(0.f, 0.f, 0.f, 0.f);
    }
  }
  __syncthreads();

  const int rg = t >> 4, cg = t & 15;          // rg 0..31 -> 2 rows each
  float acc[2][4];
#pragma unroll
  for (int i = 0; i < 2; ++i)
#pragma unroll
    for (int j = 0; j < 4; ++j) acc[i][j] = 0.f;

#pragma unroll 8
  for (int k = 0; k < 64; ++k) {
    float a[2] = {Hs[rg * 2 + 0][k], Hs[rg * 2 + 1][k]};
    float4 b = *(const float4*)&Ws[k][cg * 4];
#pragma unroll
    for (int i = 0; i < 2; ++i) {
      acc[i][0] += a[i]*b.x; acc[i][1] += a[i]*b.y;
      acc[i][2] += a[i]*b.z; acc[i][3] += a[i]*b.w;
    }
  }
#pragma unroll
  for (int i = 0; i < 2; ++i) {
    int gn = node0 + rg * 2 + i;
    if (gn < n) {
      if (OUTBF) {
        uint2 o;
        o.x = pack2bf(acc[i][0], acc[i][1]);
        o.y = pack2bf(acc[i][2], acc[i][3]);
        *(uint2*)&((unsigned short*)Outv)[(size_t)gn * 64 + cg * 4] = o;
      } else {
        float4 o = make_float4(acc[i][0], acc[i][1], acc[i][2], acc[i][3]);
        *(float4*)&((float*)Outv)[(size_t)gn * 64 + cg * 4] = o;
      }
    }
  }
}

// ======= fused gather3 + post3 (fp32 P): H4 = relu(agg(P)/deg + bc3) ========
__global__ __launch_bounds__(512) void gp_kernel(
    const float* __restrict__ P, const int* __restrict__ offs,
    const int* __restrict__ adj, const int* __restrict__ deg,
    const float* __restrict__ bc3, float* __restrict__ H4,
    float* __restrict__ stats, int n)
{
  __shared__ int offss[65];
  const int t = threadIdx.x;
  const int wave = t >> 6, lane = t & 63;
  const int g = lane >> 4, li = lane & 15;
  const int node0 = blockIdx.x * 64;
  if (t < 65) offss[t] = offs[min(node0 + t, n)];
  __syncthreads();

  const float4 bb = *(const float4*)&bc3[li * 4];
  float s[4] = {0.f, 0.f, 0.f, 0.f}, q[4] = {0.f, 0.f, 0.f, 0.f};

#pragma unroll 1
  for (int nd = 0; nd < 8; ++nd) {
    int ln = wave * 8 + nd;
    int node = node0 + ln;
    if (node >= n) break;
    float c[4];
    gather4_f32(P, adj, offss[ln], offss[ln + 1], g, li, c);
    float rd = 1.f / fmaxf((float)deg[node], 1.f);
    float4 v = make_float4(fmaxf(c[0] * rd + bb.x, 0.f),
                           fmaxf(c[1] * rd + bb.y, 0.f),
                           fmaxf(c[2] * rd + bb.z, 0.f),
                           fmaxf(c[3] * rd + bb.w, 0.f));
    if (g == 0) *(float4*)&H4[(size_t)node * 64 + li * 4] = v;
    s[0] += v.x; s[1] += v.y; s[2] += v.z; s[3] += v.w;
    q[0] += v.x*v.x; q[1] += v.y*v.y; q[2] += v.z*v.z; q[3] += v.w*v.w;
  }

  __shared__ float red[2][8][64];
  if (g == 0) {
    *(float4*)&red[0][wave][li * 4] = make_float4(s[0], s[1], s[2], s[3]);
    *(float4*)&red[1][wave][li * 4] = make_float4(q[0], q[1], q[2], q[3]);
  }
  __syncthreads();
  if (t < 128) {
    int which = t >> 6, ff = t & 63;
    float a = 0.f;
#pragma unroll
    for (int w = 0; w < 8; ++w) a += red[which][w][ff];
    atomicAdd(&stats[which * 64 + ff], a);
  }
}

// ============== CSR build: bucketed, no global scatter ======================
__global__ __launch_bounds__(256) void hist_kernel(
    const int* __restrict__ dst, int* __restrict__ G,
    float* __restrict__ stats, int nE, int B, int NB)
{
  __shared__ int h[256];
  int blk = blockIdx.x, t = threadIdx.x;
  if (blk == 0 && t < 128) stats[t] = 0.f;     // folded stats memset
  h[t] = 0;
  __syncthreads();
  int base = blk * 8192;
  int lim = min(8192, nE - base);
  for (int i = t; i < lim; i += 256)
    atomicAdd(&h[dst[base + i] >> 9], 1);
  __syncthreads();
  if (t < NB) G[t * B + blk] = h[t];
}

__global__ __launch_bounds__(256) void scan1_kernel(
    const int* __restrict__ in, int* __restrict__ out,
    int* __restrict__ bsum, int n)
{
  __shared__ int sh[256];
  int t = threadIdx.x;
  int i = blockIdx.x * 256 + t;
  int c = (i < n) ? in[i] : 0;
  sh[t] = c;
  __syncthreads();
#pragma unroll
  for (int off = 1; off < 256; off <<= 1) {
    int v = 0;
    if (t >= off) v = sh[t - off];
    __syncthreads();
    if (t >= off) sh[t] += v;
    __syncthreads();
  }
  if (i < n) out[i] = sh[t] - c;
  if (t == 255) bsum[blockIdx.x] = sh[255];
}

__global__ __launch_bounds__(256) void scan2_kernel(int* __restrict__ bsum, int nb)
{
  __shared__ int sh[256];
  __shared__ int carry;
  int t = threadIdx.x;
  if (t == 0) carry = 0;
  __syncthreads();
  for (int base = 0; base < nb; base += 256) {
    int i = base + t;
    int v = (i < nb) ? bsum[i] : 0;
    sh[t] = v;
    __syncthreads();
#pragma unroll
    for (int off = 1; off < 256; off <<= 1) {
      int u = 0;
      if (t >= off) u = sh[t - off];
      __syncthreads();
      if (t >= off) sh[t] += u;
      __syncthreads();
    }
    int c0 = carry;
    int incl = sh[t], total = sh[255];
    if (i < nb) bsum[i] = c0 + incl - v;
    __syncthreads();
    if (t == 0) carry = c0 + total;
    __syncthreads();
  }
  if (t == 0) bsum[nb] = carry;
}

// scatter edges into bucket-major pair array; block-exclusive regions
__global__ __launch_bounds__(256) void scatter2_kernel(
    const int* __restrict__ src, const int* __restrict__ dst,
    const int* __restrict__ W, const int* __restrict__ bsum,
    int2* __restrict__ EP, int nE, int B, int NB)
{
  __shared__ int cur[256];
  int blk = blockIdx.x, t = threadIdx.x;
  if (t < NB) {
    int gi = t * B + blk;
    cur[t] = W[gi] + bsum[gi >> 8];
  }
  __syncthreads();
  int base = blk * 8192;
  int lim = min(8192, nE - base);
  for (int i = t; i < lim; i += 256) {
    int s = src[base + i], d = dst[base + i];
    int slot = atomicAdd(&cur[d >> 9], 1);
    EP[slot] = make_int2(s, d);
  }
}

// per-bucket: cnt/offs from LDS hist+scan; adj fill in block-local window
__global__ __launch_bounds__(256) void fillc_kernel(
    const int2* __restrict__ EP, const int* __restrict__ W,
    const int* __restrict__ bsum,
    int* __restrict__ cnt, int* __restrict__ offs, int* __restrict__ adj,
    int n, int nE, int B, int NB)
{
  __shared__ int h[512];
  int b = blockIdx.x, t = threadIdx.x;
  int g0i = b * B;
  int segStart = W[g0i] + bsum[g0i >> 8];
  int segEnd = (b == NB - 1) ? nE : (W[g0i + B] + bsum[(g0i + B) >> 8]);
  int nodeBase = b << 9;

  h[t] = 0; h[t + 256] = 0;
  __syncthreads();
  for (int i = segStart + t; i < segEnd; i += 256)
    atomicAdd(&h[EP[i].y - nodeBase], 1);
  __syncthreads();
  int c0 = h[t], c1 = h[t + 256];
#pragma unroll
  for (int off = 1; off < 512; off <<= 1) {
    int a = (t >= off) ? h[t - off] : 0;
    int bb = (t + 256 >= off) ? h[t + 256 - off] : 0;
    __syncthreads();
    h[t] += a; h[t + 256] += bb;
    __syncthreads();
  }
  int e0 = h[t] - c0, e1 = h[t + 256] - c1;   // exclusive
  int g0 = nodeBase + t, g1 = nodeBase + t + 256;
  if (g0 < n) { cnt[g0] = c0; offs[g0] = segStart + e0; }
  if (g1 < n) { cnt[g1] = c1; offs[g1] = segStart + e1; }
  if (b == 0 && t == 0) offs[n] = nE;
  __syncthreads();
  h[t] = e0; h[t + 256] = e1;                 // cursors
  __syncthreads();
  for (int i = segStart + t; i < segEnd; i += 256) {
    int2 p = EP[i];
    int slot = atomicAdd(&h[p.y - nodeBase], 1);
    adj[segStart + slot] = p.x;
  }
}

// ---- fold batchnorm into W2 ------------------------------------------------
__global__ __launch_bounds__(256) void fold_kernel(
    const float* __restrict__ stats, const float* __restrict__ gamma,
    const float* __restrict__ beta, const float* __restrict__ W2,
    const float* __restrict__ b2, float* __restrict__ W2f,
    float* __restrict__ b2f, int n)
{
  __shared__ float rsg[64], corr[64];
  int t = threadIdx.x;
  if (t < 64) {
    float m = stats[t] / (float)n;
    float var = stats[64 + t] / (float)n - m * m;
    float rs = rsqrtf(var + 1e-5f);
    float g = gamma[t] * rs;
    rsg[t] = g;
    corr[t] = beta[t] - m * g;
  }
  __syncthreads();
#pragma unroll
  for (int i = 0; i < 8; ++i) {
    int lin = t + i * 256;
    int k = lin >> 5;
    W2f[lin] = rsg[k] * W2[lin];
  }
  if (t < 32) {
    float a = b2[t];
    for (int k = 0; k < 64; ++k) a += corr[k] * W2[k * 32 + t];
    b2f[t] = a;
  }
}

// ---- final: out = relu(H4 @ W2f + b2f) @ W3 + b3 ---------------------------
__global__ __launch_bounds__(256) void final_kernel(
    const float* __restrict__ H4, const float* __restrict__ W2f,
    const float* __restrict__ b2f, const float* __restrict__ W3,
    const float* __restrict__ b3, float* __restrict__ Out, int n)
{
  __shared__ float Hs[64][68];
  __shared__ float W2s[64][32];
  __shared__ float W3s[32][32];
  __shared__ float Us[64][36];
  __shared__ float b2s[32], b3s[32];
  const int t = threadIdx.x;
  const int node0 = blockIdx.x * 64;

#pragma unroll
  for (int i = 0; i < 4; ++i) {
    int lin = t + i * 256;
    int node = lin >> 4, kq = lin & 15;
    float4 v = make_float4(0.f, 0.f, 0.f, 0.f);
    if (node0 + node < n)
      v = *(const float4*)&H4[(size_t)(node0 + node) * 64 + kq * 4];
    *(float4*)&Hs[node][kq * 4] = v;
  }
#pragma unroll
  for (int i = 0; i < 2; ++i) {
    int lin = t + i * 256;
    ((float4*)&W2s[0][0])[lin] = ((const float4*)W2f)[lin];
  }
  ((float4*)&W3s[0][0])[t & 255] = ((const float4*)W3)[t & 255];
  if (t < 32) { b2s[t] = b2f[t]; b3s[t] = b3[t]; }
  __syncthreads();

  const int rg = t >> 4, cg = t & 15;
  float acc[4][2] = {{0.f,0.f},{0.f,0.f},{0.f,0.f},{0.f,0.f}};
#pragma unroll 8
  for (int k = 0; k < 64; ++k) {
    float a[4] = {Hs[rg*4+0][k], Hs[rg*4+1][k], Hs[rg*4+2][k], Hs[rg*4+3][k]};
    float w0 = W2s[k][cg*2], w1 = W2s[k][cg*2+1];
#pragma unroll
    for (int i = 0; i < 4; ++i) { acc[i][0] += a[i]*w0; acc[i][1] += a[i]*w1; }
  }
#pragma unroll
  for (int i = 0; i < 4; ++i) {
    Us[rg*4+i][cg*2+0] = fmaxf(acc[i][0] + b2s[cg*2+0], 0.f);
    Us[rg*4+i][cg*2+1] = fmaxf(acc[i][1] + b2s[cg*2+1], 0.f);
  }
  __syncthreads();

  float acc2[4][2] = {{0.f,0.f},{0.f,0.f},{0.f,0.f},{0.f,0.f}};
#pragma unroll
  for (int k = 0; k < 32; ++k) {
    float a[4] = {Us[rg*4+0][k], Us[rg*4+1][k], Us[rg*4+2][k], Us[rg*4+3][k]};
    float w0 = W3s[k][cg*2], w1 = W3s[k][cg*2+1];
#pragma unroll
    for (int i = 0; i < 4; ++i) { acc2[i][0] += a[i]*w0; acc2[i][1] += a[i]*w1; }
  }
  float (*Os)[36] = (float(*)[36])Hs;
#pragma unroll
  for (int i = 0; i < 4; ++i) {
    Os[rg*4+i][cg*2+0] = acc2[i][0] + b3s[cg*2+0];
    Os[rg*4+i][cg*2+1] = acc2[i][1] + b3s[cg*2+1];
  }
  __syncthreads();
#pragma unroll
  for (int i = 0; i < 2; ++i) {
    int lin = t + i * 256;
    int node = lin >> 3, c4 = lin & 7;
    if (node0 + node < n)
      *(float4*)&Out[(size_t)(node0 + node) * 32 + c4 * 4] =
          *(float4*)&Os[node][c4 * 4];
  }
}

// ---------------------------------------------------------------------------
extern "C" void kernel_launch(void* const* d_in, const int* in_sizes, int n_in,
                              void* d_out, int out_size, void* d_ws, size_t ws_size,
                              hipStream_t stream)
{
  const float* X     = (const float*)d_in[0];
  const float* W1    = (const float*)d_in[1];
  const float* b1    = (const float*)d_in[2];
  const float* Wc1   = (const float*)d_in[3];
  const float* bc1   = (const float*)d_in[4];
  const float* Wc2   = (const float*)d_in[5];
  const float* bc2   = (const float*)d_in[6];
  const float* Wc3   = (const float*)d_in[7];
  const float* bc3   = (const float*)d_in[8];
  const float* gamma = (const float*)d_in[9];
  const float* beta  = (const float*)d_in[10];
  const float* W2    = (const float*)d_in[11];
  const float* b2    = (const float*)d_in[12];
  const float* W3    = (const float*)d_in[13];
  const float* b3    = (const float*)d_in[14];
  const int*   ei    = (const int*)d_in[15];

  const int n  = in_sizes[0] / F_IN;
  const int nE = in_sizes[15] / 2;
  const int* src  = ei;
  const int* dstv = ei + nE;

  const int NB = (n + 511) >> 9;          // buckets of 512 nodes
  const int B  = (nE + 8191) >> 13;       // chunks of 8192 edges
  const int NG = NB * B;
  const int nbG = (NG + 255) / 256;

  char* wsb = (char*)d_ws;
  unsigned short* Pa = (unsigned short*)wsb;               // n*64 bf16
  unsigned short* Pb = (unsigned short*)(wsb + (size_t)n * 128); // n*64 bf16
  float* Pc    = (float*)(wsb + (size_t)n * 256);          // n*64 fp32
  float* H4    = (float*)(wsb + (size_t)n * 512);          // n*64 fp32
  float* stats = H4 + (size_t)n * 64;                      // 128
  float* W2f   = stats + 128;                              // 2048
  float* b2f   = W2f + 2048;                               // 32
  int*   cnt   = (int*)(b2f + 32);                         // n
  int*   offs  = cnt + n;                                  // n+1
  int*   G     = offs + n + 1;                             // NG
  int*   W     = G + NG;                                   // NG+1
  int*   bsum  = W + NG + 1;                               // nbG+1
  int*   adj   = bsum + nbG + 1;                           // nE
  uintptr_t epAddr = ((uintptr_t)(adj + nE) + 7) & ~(uintptr_t)7;
  int2*  EP    = (int2*)epAddr;                            // nE pairs
  short8* Wt2  = (short8*)(EP + nE);                       // 128KB

  const int nb  = (n + 63) / 64;

  // W1 -> fragment-linear bf16, then fused lin1+conv1 (H1 never hits HBM)
  wt_kernel<<<32, 256, 0, stream>>>(W1, Wt2);
  l1c1_kernel<<<nb, 256, 0, stream>>>(X, Wt2, b1, Wc1, Pa, n);

  // CSR build (bucketed, no global scatter; scan3 folded into read sites)
  hist_kernel<<<B, 256, 0, stream>>>(dstv, G, stats, nE, B, NB);
  scan1_kernel<<<nbG, 256, 0, stream>>>(G, W, bsum, NG);
  scan2_kernel<<<1, 256, 0, stream>>>(bsum, nbG);
  scatter2_kernel<<<B, 256, 0, stream>>>(src, dstv, W, bsum, EP, nE, B, NB);
  fillc_kernel<<<NB, 256, 0, stream>>>(EP, W, bsum, cnt, offs, adj, n, nE, B, NB);

  // conv2: Pb(bf16) = relu(agg(Pa bf16)/deg + bc1) @ Wc2
  gmm_kernel<true, true><<<nb, 512, 0, stream>>>(
      Pa, offs, adj, cnt, bc1, Wc2, Pb, n);

  // conv3: Pc(fp32) = relu(agg(Pb bf16)/deg + bc2) @ Wc3
  gmm_kernel<true, false><<<nb, 512, 0, stream>>>(
      Pb, offs, adj, cnt, bc2, Wc3, Pc, n);

  // conv3 epilogue: H4 = relu(agg(Pc fp32)/deg + bc3); batch stats
  gp_kernel<<<nb, 512, 0, stream>>>(Pc, offs, adj, cnt, bc3, H4, stats, n);

  // fold batchnorm into W2, then fused lin2+lin3
  fold_kernel<<<1, 256, 0, stream>>>(stats, gamma, beta, W2, b2, W2f, b2f, n);
  final_kernel<<<nb, 256, 0, stream>>>(H4, W2f, b2f, W3, b3, (float*)d_out, n);
}

// Round 9
// 592.832 us; speedup vs baseline: 1.1218x; 1.1218x over previous
//
#include <hip/hip_runtime.h>
#include <cstdint>
#include <cstddef>

constexpr int F_IN  = 512;
constexpr int D_EMB = 128;
constexpr int D_HID = 64;
constexpr int N_CLS = 32;

typedef __attribute__((ext_vector_type(8))) short short8;
typedef __attribute__((ext_vector_type(4))) float floatx4;

__device__ inline unsigned short f2bf(float f) {
  union { float f; uint32_t u; } v; v.f = f;
  uint32_t r = v.u + 0x7FFF + ((v.u >> 16) & 1);   // round-to-nearest-even
  return (unsigned short)(r >> 16);
}

__device__ inline uint32_t pack2bf(float lo, float hi) {
  return ((uint32_t)f2bf(hi) << 16) | (uint32_t)f2bf(lo);
}

// ---- W1 -> fragment-linear bf16: Wt2[kc8][ct][ks][lane] of short8 ----------
__global__ __launch_bounds__(256) void wt_kernel(
    const float* __restrict__ W1, short8* __restrict__ Wt2)
{
  int idx = blockIdx.x * 256 + threadIdx.x;     // 0..8191
  int kc8 = idx >> 10, lin = idx & 1023;
  int ct = lin >> 7, rem = lin & 127, ks = rem >> 6, ln = rem & 63;
  int col = ct * 16 + (ln & 15);
  int k0 = kc8 * 64 + ks * 32 + (ln >> 4) * 8;
  short8 s;
#pragma unroll
  for (int j = 0; j < 8; ++j)
    s[j] = (short)f2bf(W1[(size_t)(k0 + j) * D_EMB + col]);
  Wt2[idx] = s;
}

// ---- fused lin1 + conv1-mm: P(bf16) = relu(X @ W1 + b1) @ Wc1 --------------
__global__ __launch_bounds__(256) void l1c1_kernel(
    const float* __restrict__ X, const short8* __restrict__ Wt2,
    const float* __restrict__ b1, const float* __restrict__ Wc1,
    unsigned short* __restrict__ P, int n)
{
  __shared__ __align__(16) char smem[50176];
  short8* Xs = (short8*)smem;                      // 8 KB   (phase 1)
  short8* Ws = (short8*)(smem + 8192);             // 16 KB  (phase 1)
  float (*Hs)[132] = (float(*)[132])smem;          // 33792B (phase 2, aliases)
  float (*Wc)[64]  = (float(*)[64])(smem + 33792); // 16 KB  (phase 2)

  const int t = threadIdx.x;
  const int wave = t >> 6, lane = t & 63;
  const int quad = lane >> 4, mrow = lane & 15;
  const int node0 = blockIdx.x * 64;
  const int cw = wave * 2;                         // col-tile base (2 per wave)

  // phase-2 Wc1 half-0 prefetch: issued now, consumed after the K-loop
  float4 wp[4];
#pragma unroll
  for (int i = 0; i < 4; ++i) wp[i] = ((const float4*)Wc1)[i * 256 + t];

  // X staging assignment: g = t + i*256 (i<2); row = g>>3, col8 = g&7
  const float* sp[2];
  int soff[2];
#pragma unroll
  for (int i = 0; i < 2; ++i) {
    int g = t + i * 256;
    int row = g >> 3, col8 = g & 7;
    soff[i] = row * 128 + ((col8 * 16) ^ ((row & 7) << 4));
    int gr = node0 + row; if (gr >= n) gr = n - 1;
    sp[i] = &X[(size_t)gr * F_IN + col8 * 8];
  }

  floatx4 acc[4][2];
#pragma unroll
  for (int i = 0; i < 4; ++i)
#pragma unroll
    for (int j = 0; j < 2; ++j) acc[i][j] = (floatx4){0.f, 0.f, 0.f, 0.f};

  float4 xrA[2][2], xrB[2][2];    // 2-deep X prefetch (tiles k, k+1)
  short8 wrA[4], wrB[4];          // 2-deep W prefetch

#pragma unroll
  for (int i = 0; i < 2; ++i) {   // prologue: tiles 0 and 1
    xrA[i][0] = *(const float4*)sp[i];
    xrA[i][1] = *(const float4*)(sp[i] + 4);
    xrB[i][0] = *(const float4*)(sp[i] + 64);
    xrB[i][1] = *(const float4*)(sp[i] + 68);
  }
#pragma unroll
  for (int i = 0; i < 4; ++i) {
    wrA[i] = Wt2[t + i * 256];
    wrB[i] = Wt2[1024 + t + i * 256];
  }

  auto substep = [&](float4 (&xr)[2][2], short8 (&wr)[4], int knext) {
    short8 s8[2];
#pragma unroll
    for (int i = 0; i < 2; ++i) {
      s8[i][0] = (short)f2bf(xr[i][0].x); s8[i][1] = (short)f2bf(xr[i][0].y);
      s8[i][2] = (short)f2bf(xr[i][0].z); s8[i][3] = (short)f2bf(xr[i][0].w);
      s8[i][4] = (short)f2bf(xr[i][1].x); s8[i][5] = (short)f2bf(xr[i][1].y);
      s8[i][6] = (short)f2bf(xr[i][1].z); s8[i][7] = (short)f2bf(xr[i][1].w);
    }
    __syncthreads();                      // WAR: prev tile's compute done
#pragma unroll
    for (int i = 0; i < 2; ++i)
      *(short8*)((char*)Xs + soff[i]) = s8[i];
#pragma unroll
    for (int i = 0; i < 4; ++i)
      Ws[t + i * 256] = wr[i];
    __syncthreads();                      // tile visible

    if (knext < 8) {                      // refill this buffer, 2 tiles ahead
#pragma unroll
      for (int i = 0; i < 2; ++i) {
        const float* p = sp[i] + knext * 64;
        xr[i][0] = *(const float4*)p;
        xr[i][1] = *(const float4*)(p + 4);
      }
#pragma unroll
      for (int i = 0; i < 4; ++i)
        wr[i] = Wt2[knext * 1024 + t + i * 256];
    }

#pragma unroll
    for (int ks = 0; ks < 2; ++ks) {
      short8 af[4], bf[2];
#pragma unroll
      for (int rt = 0; rt < 4; ++rt) {
        int row = rt * 16 + mrow;
        int byteoff = row * 128 + ((ks * 64 + quad * 16) ^ ((row & 7) << 4));
        af[rt] = *(const short8*)((const char*)Xs + byteoff);
      }
#pragma unroll
      for (int c = 0; c < 2; ++c)
        bf[c] = Ws[((cw + c) * 2 + ks) * 64 + lane];
#pragma unroll
      for (int rt = 0; rt < 4; ++rt)
#pragma unroll
        for (int c = 0; c < 2; ++c)
          acc[rt][c] = __builtin_amdgcn_mfma_f32_16x16x32_bf16(
              af[rt], bf[c], acc[rt][c], 0, 0, 0);
    }
  };

#pragma unroll 1
  for (int kc8 = 0; kc8 < 8; kc8 += 2) {
    substep(xrA, wrA, kc8 + 2);
    substep(xrB, wrB, kc8 + 3);
  }

  // ---------------- phase 2: P-tile = relu(H1-tile) @ Wc1 -------------------
  __syncthreads();                        // all Xs/Ws reads complete (alias!)
#pragma unroll
  for (int ct = 0; ct < 2; ++ct) {
    int col = (cw + ct) * 16 + mrow;
    float b = b1[col];
#pragma unroll
    for (int rt = 0; rt < 4; ++rt)
#pragma unroll
      for (int r = 0; r < 4; ++r)
        Hs[rt * 16 + quad * 4 + r][col] = fmaxf(acc[rt][ct][r] + b, 0.f);
  }
#pragma unroll
  for (int i = 0; i < 4; ++i)             // Wc1 half 0 into LDS
    ((float4*)&Wc[0][0])[i * 256 + t] = wp[i];
  __syncthreads();

#pragma unroll
  for (int i = 0; i < 4; ++i)             // prefetch Wc1 half 1
    wp[i] = ((const float4*)Wc1)[1024 + i * 256 + t];

  const int rg = t >> 4, cg = t & 15;
  float acc2[4][4];
#pragma unroll
  for (int i = 0; i < 4; ++i)
#pragma unroll
    for (int j = 0; j < 4; ++j) acc2[i][j] = 0.f;

#pragma unroll 8
  for (int k = 0; k < 64; ++k) {          // k = 0..63
    float a[4] = {Hs[rg*4+0][k], Hs[rg*4+1][k], Hs[rg*4+2][k], Hs[rg*4+3][k]};
    float4 b = *(const float4*)&Wc[k][cg * 4];
#pragma unroll
    for (int i = 0; i < 4; ++i) {
      acc2[i][0] += a[i]*b.x; acc2[i][1] += a[i]*b.y;
      acc2[i][2] += a[i]*b.z; acc2[i][3] += a[i]*b.w;
    }
  }
  __syncthreads();
#pragma unroll
  for (int i = 0; i < 4; ++i)             // Wc1 half 1 into LDS
    ((float4*)&Wc[0][0])[i * 256 + t] = wp[i];
  __syncthreads();

#pragma unroll 8
  for (int k = 0; k < 64; ++k) {          // k = 64..127
    float a[4] = {Hs[rg*4+0][64+k], Hs[rg*4+1][64+k],
                  Hs[rg*4+2][64+k], Hs[rg*4+3][64+k]};
    float4 b = *(const float4*)&Wc[k][cg * 4];
#pragma unroll
    for (int i = 0; i < 4; ++i) {
      acc2[i][0] += a[i]*b.x; acc2[i][1] += a[i]*b.y;
      acc2[i][2] += a[i]*b.z; acc2[i][3] += a[i]*b.w;
    }
  }
#pragma unroll
  for (int i = 0; i < 4; ++i) {
    int gn = node0 + rg * 4 + i;
    if (gn < n) {
      uint2 o;
      o.x = pack2bf(acc2[i][0], acc2[i][1]);
      o.y = pack2bf(acc2[i][2], acc2[i][3]);
      *(uint2*)&P[(size_t)gn * 64 + cg * 4] = o;
    }
  }
}

// ---- bf16 2-row gather core (round-7 proven): 2 lane-groups of 32 ----------
__device__ inline void gather2_bf(
    const unsigned short* __restrict__ P, const int* __restrict__ adj,
    int beg, int end, int g, int li, float& c0, float& c1)
{
  c0 = 0.f; c1 = 0.f;
  if (end > beg) {
    int e1 = end - 1;
    for (int jj = beg + g; jj < end; jj += 16) {
#pragma unroll
      for (int k = 0; k < 8; ++k) {
        int e = jj + 2 * k;
        int ec = min(e, e1);
        int idx = adj[ec];
        uint32_t u = *(const uint32_t*)&P[(size_t)idx * 64 + li * 2];
        float lo = __uint_as_float(u << 16);
        float hi = __uint_as_float(u & 0xFFFF0000u);
        bool p = e < end;
        c0 += p ? lo : 0.f;
        c1 += p ? hi : 0.f;
      }
    }
  }
  c0 += __shfl_xor(c0, 32, 64);
  c1 += __shfl_xor(c1, 32, 64);
}

// ---- fp32 wide gather: 4 lane-groups of 16, float4/lane, 4-deep ------------
// Granularity = 16 edges (matches mean degree, same waste as round-7);
// 16B/instr per lane (4x fewer VMEM instructions than dword gather);
// only 4 live float4 temporaries (half of the failed round-8 config).
__device__ inline void gather4_f32(
    const float* __restrict__ P, const int* __restrict__ adj,
    int beg, int end, int g4, int li, float c[4])
{
  c[0] = 0.f; c[1] = 0.f; c[2] = 0.f; c[3] = 0.f;
  if (end > beg) {
    int e1 = end - 1;
    for (int jj = beg + g4; jj < end; jj += 16) {
#pragma unroll
      for (int k = 0; k < 4; ++k) {
        int e = jj + 4 * k;
        int ec = min(e, e1);
        int idx = adj[ec];
        float4 u = *(const float4*)&P[(size_t)idx * 64 + li * 4];
        bool p = e < end;
        c[0] += p ? u.x : 0.f;
        c[1] += p ? u.y : 0.f;
        c[2] += p ? u.z : 0.f;
        c[3] += p ? u.w : 0.f;
      }
    }
  }
#pragma unroll
  for (int i = 0; i < 4; ++i) {
    c[i] += __shfl_xor(c[i], 16, 64);
    c[i] += __shfl_xor(c[i], 32, 64);
  }
}

// ======= fused gather + pre + matmul: Out = pre(agg(P bf16)) @ W ============
// deg computed from offs diff (cnt array eliminated).
template<bool OUTBF>
__global__ __launch_bounds__(512) void gmm_kernel(
    const unsigned short* __restrict__ P, const int* __restrict__ offs,
    const int* __restrict__ adj,
    const float* __restrict__ bin, const float* __restrict__ W,
    void* __restrict__ Outv, int n)
{
  __shared__ float Hs[64][68];
  __shared__ float Ws[64][64];
  __shared__ int offss[65];
  const int t = threadIdx.x;
  const int wave = t >> 6, lane = t & 63;
  const int g = lane >> 5, li = lane & 31;
  const int node0 = blockIdx.x * 64;

#pragma unroll
  for (int i = 0; i < 2; ++i) {
    int lin = t + i * 512;
    ((float4*)&Ws[0][0])[lin] = ((const float4*)W)[lin];
  }
  if (t < 65) offss[t] = offs[min(node0 + t, n)];
  __syncthreads();

  const float2 bb = *(const float2*)&bin[li * 2];

#pragma unroll 1
  for (int nd = 0; nd < 8; ++nd) {
    int ln = wave * 8 + nd;
    int node = node0 + ln;
    if (node < n) {
      float c0, c1;
      int beg = offss[ln], end = offss[ln + 1];
      gather2_bf(P, adj, beg, end, g, li, c0, c1);
      float rd = 1.f / fmaxf((float)(end - beg), 1.f);
      float v0 = fmaxf(c0 * rd + bb.x, 0.f);
      float v1 = fmaxf(c1 * rd + bb.y, 0.f);
      if (g == 0) *(float2*)&Hs[ln][li * 2] = make_float2(v0, v1);
    } else if (g == 0) {
      *(float2*)&Hs[ln][li * 2] = make_float2(0.f, 0.f);
    }
  }
  __syncthreads();

  const int rg = t >> 4, cg = t & 15;          // rg 0..31 -> 2 rows each
  float acc[2][4];
#pragma unroll
  for (int i = 0; i < 2; ++i)
#pragma unroll
    for (int j = 0; j < 4; ++j) acc[i][j] = 0.f;

#pragma unroll 8
  for (int k = 0; k < 64; ++k) {
    float a[2] = {Hs[rg * 2 + 0][k], Hs[rg * 2 + 1][k]};
    float4 b = *(const float4*)&Ws[k][cg * 4];
#pragma unroll
    for (int i = 0; i < 2; ++i) {
      acc[i][0] += a[i]*b.x; acc[i][1] += a[i]*b.y;
      acc[i][2] += a[i]*b.z; acc[i][3] += a[i]*b.w;
    }
  }
#pragma unroll
  for (int i = 0; i < 2; ++i) {
    int gn = node0 + rg * 2 + i;
    if (gn < n) {
      if (OUTBF) {
        uint2 o;
        o.x = pack2bf(acc[i][0], acc[i][1]);
        o.y = pack2bf(acc[i][2], acc[i][3]);
        *(uint2*)&((unsigned short*)Outv)[(size_t)gn * 64 + cg * 4] = o;
      } else {
        float4 o = make_float4(acc[i][0], acc[i][1], acc[i][2], acc[i][3]);
        *(float4*)&((float*)Outv)[(size_t)gn * 64 + cg * 4] = o;
      }
    }
  }
}

// ======= fused gather3 + post3 (fp32 P, wide gather): H4 + stats ============
__global__ __launch_bounds__(512) void gp_kernel(
    const float* __restrict__ P, const int* __restrict__ offs,
    const int* __restrict__ adj,
    const float* __restrict__ bc3, float* __restrict__ H4,
    float* __restrict__ stats, int n)
{
  __shared__ int offss[65];
  const int t = threadIdx.x;
  const int wave = t >> 6, lane = t & 63;
  const int g4 = lane >> 4, li = lane & 15;
  const int node0 = blockIdx.x * 64;
  if (t < 65) offss[t] = offs[min(node0 + t, n)];
  __syncthreads();

  const float4 bb = *(const float4*)&bc3[li * 4];
  float s[4] = {0.f, 0.f, 0.f, 0.f}, q[4] = {0.f, 0.f, 0.f, 0.f};

#pragma unroll 1
  for (int nd = 0; nd < 8; ++nd) {
    int ln = wave * 8 + nd;
    int node = node0 + ln;
    if (node >= n) break;
    float c[4];
    int beg = offss[ln], end = offss[ln + 1];
    gather4_f32(P, adj, beg, end, g4, li, c);
    float rd = 1.f / fmaxf((float)(end - beg), 1.f);
    float4 v = make_float4(fmaxf(c[0] * rd + bb.x, 0.f),
                           fmaxf(c[1] * rd + bb.y, 0.f),
                           fmaxf(c[2] * rd + bb.z, 0.f),
                           fmaxf(c[3] * rd + bb.w, 0.f));
    if (g4 == 0) *(float4*)&H4[(size_t)node * 64 + li * 4] = v;
    s[0] += v.x; s[1] += v.y; s[2] += v.z; s[3] += v.w;
    q[0] += v.x*v.x; q[1] += v.y*v.y; q[2] += v.z*v.z; q[3] += v.w*v.w;
  }

  __shared__ float red[2][8][64];
  if (g4 == 0) {
    *(float4*)&red[0][wave][li * 4] = make_float4(s[0], s[1], s[2], s[3]);
    *(float4*)&red[1][wave][li * 4] = make_float4(q[0], q[1], q[2], q[3]);
  }
  __syncthreads();
  if (t < 128) {
    int which = t >> 6, ff = t & 63;
    float a = 0.f;
#pragma unroll
    for (int w = 0; w < 8; ++w) a += red[which][w][ff];
    atomicAdd(&stats[which * 64 + ff], a);
  }
}

// ============== CSR build: bucketed, no global scatter ======================
__global__ __launch_bounds__(256) void hist_kernel(
    const int* __restrict__ dst, int* __restrict__ G,
    float* __restrict__ stats, int nE, int B, int NB)
{
  __shared__ int h[256];
  int blk = blockIdx.x, t = threadIdx.x;
  if (blk == 0 && t < 128) stats[t] = 0.f;     // folded stats memset
  h[t] = 0;
  __syncthreads();
  int base = blk * 8192;
  int lim = min(8192, nE - base);
  for (int i = t; i < lim; i += 256)
    atomicAdd(&h[dst[base + i] >> 9], 1);
  __syncthreads();
  if (t < NB) G[t * B + blk] = h[t];
}

__global__ __launch_bounds__(256) void scan1_kernel(
    const int* __restrict__ in, int* __restrict__ out,
    int* __restrict__ bsum, int n)
{
  __shared__ int sh[256];
  int t = threadIdx.x;
  int i = blockIdx.x * 256 + t;
  int c = (i < n) ? in[i] : 0;
  sh[t] = c;
  __syncthreads();
#pragma unroll
  for (int off = 1; off < 256; off <<= 1) {
    int v = 0;
    if (t >= off) v = sh[t - off];
    __syncthreads();
    if (t >= off) sh[t] += v;
    __syncthreads();
  }
  if (i < n) out[i] = sh[t] - c;
  if (t == 255) bsum[blockIdx.x] = sh[255];
}

__global__ __launch_bounds__(256) void scan2_kernel(int* __restrict__ bsum, int nb)
{
  __shared__ int sh[256];
  __shared__ int carry;
  int t = threadIdx.x;
  if (t == 0) carry = 0;
  __syncthreads();
  for (int base = 0; base < nb; base += 256) {
    int i = base + t;
    int v = (i < nb) ? bsum[i] : 0;
    sh[t] = v;
    __syncthreads();
#pragma unroll
    for (int off = 1; off < 256; off <<= 1) {
      int u = 0;
      if (t >= off) u = sh[t - off];
      __syncthreads();
      if (t >= off) sh[t] += u;
      __syncthreads();
    }
    int c0 = carry;
    int incl = sh[t], total = sh[255];
    if (i < nb) bsum[i] = c0 + incl - v;
    __syncthreads();
    if (t == 0) carry = c0 + total;
    __syncthreads();
  }
  if (t == 0) bsum[nb] = carry;
}

// scatter edges into bucket-major PACKED array: EP = (s<<9) | (d&511)
// (s < 2^17, local dst < 2^9 => fits 26 bits; halves EP traffic vs int2)
__global__ __launch_bounds__(256) void scatter2_kernel(
    const int* __restrict__ src, const int* __restrict__ dst,
    const int* __restrict__ W, const int* __restrict__ bsum,
    int* __restrict__ EP, int nE, int B, int NB)
{
  __shared__ int cur[256];
  int blk = blockIdx.x, t = threadIdx.x;
  if (t < NB) {
    int gi = t * B + blk;
    cur[t] = W[gi] + bsum[gi >> 8];
  }
  __syncthreads();
  int base = blk * 8192;
  int lim = min(8192, nE - base);
  for (int i = t; i < lim; i += 256) {
    int s = src[base + i], d = dst[base + i];
    int slot = atomicAdd(&cur[d >> 9], 1);
    EP[slot] = (s << 9) | (d & 511);
  }
}

// per-bucket: offs from LDS hist+scan; adj fill in block-local window
// (cnt array eliminated: deg = offs diff at consumers)
__global__ __launch_bounds__(256) void fillc_kernel(
    const int* __restrict__ EP, const int* __restrict__ W,
    const int* __restrict__ bsum,
    int* __restrict__ offs, int* __restrict__ adj,
    int n, int nE, int B, int NB)
{
  __shared__ int h[512];
  int b = blockIdx.x, t = threadIdx.x;
  int g0i = b * B;
  int segStart = W[g0i] + bsum[g0i >> 8];
  int segEnd = (b == NB - 1) ? nE : (W[g0i + B] + bsum[(g0i + B) >> 8]);
  int nodeBase = b << 9;

  h[t] = 0; h[t + 256] = 0;
  __syncthreads();
  for (int i = segStart + t; i < segEnd; i += 256)
    atomicAdd(&h[EP[i] & 511], 1);
  __syncthreads();
  int c0 = h[t], c1 = h[t + 256];
#pragma unroll
  for (int off = 1; off < 512; off <<= 1) {
    int a = (t >= off) ? h[t - off] : 0;
    int bb = (t + 256 >= off) ? h[t + 256 - off] : 0;
    __syncthreads();
    h[t] += a; h[t + 256] += bb;
    __syncthreads();
  }
  int e0 = h[t] - c0, e1 = h[t + 256] - c1;   // exclusive
  int g0 = nodeBase + t, g1 = nodeBase + t + 256;
  if (g0 < n) offs[g0] = segStart + e0;
  if (g1 < n) offs[g1] = segStart + e1;
  if (b == 0 && t == 0) offs[n] = nE;
  __syncthreads();
  h[t] = e0; h[t + 256] = e1;                 // cursors
  __syncthreads();
  for (int i = segStart + t; i < segEnd; i += 256) {
    int u = EP[i];
    int slot = atomicAdd(&h[u & 511], 1);
    adj[segStart + slot] = u >> 9;
  }
}

// ---- fold batchnorm into W2 ------------------------------------------------
__global__ __launch_bounds__(256) void fold_kernel(
    const float* __restrict__ stats, const float* __restrict__ gamma,
    const float* __restrict__ beta, const float* __restrict__ W2,
    const float* __restrict__ b2, float* __restrict__ W2f,
    float* __restrict__ b2f, int n)
{
  __shared__ float rsg[64], corr[64];
  int t = threadIdx.x;
  if (t < 64) {
    float m = stats[t] / (float)n;
    float var = stats[64 + t] / (float)n - m * m;
    float rs = rsqrtf(var + 1e-5f);
    float g = gamma[t] * rs;
    rsg[t] = g;
    corr[t] = beta[t] - m * g;
  }
  __syncthreads();
#pragma unroll
  for (int i = 0; i < 8; ++i) {
    int lin = t + i * 256;
    int k = lin >> 5;
    W2f[lin] = rsg[k] * W2[lin];
  }
  if (t < 32) {
    float a = b2[t];
    for (int k = 0; k < 64; ++k) a += corr[k] * W2[k * 32 + t];
    b2f[t] = a;
  }
}

// ---- final: out = relu(H4 @ W2f + b2f) @ W3 + b3 ---------------------------
__global__ __launch_bounds__(256) void final_kernel(
    const float* __restrict__ H4, const float* __restrict__ W2f,
    const float* __restrict__ b2f, const float* __restrict__ W3,
    const float* __restrict__ b3, float* __restrict__ Out, int n)
{
  __shared__ float Hs[64][68];
  __shared__ float W2s[64][32];
  __shared__ float W3s[32][32];
  __shared__ float Us[64][36];
  __shared__ float b2s[32], b3s[32];
  const int t = threadIdx.x;
  const int node0 = blockIdx.x * 64;

#pragma unroll
  for (int i = 0; i < 4; ++i) {
    int lin = t + i * 256;
    int node = lin >> 4, kq = lin & 15;
    float4 v = make_float4(0.f, 0.f, 0.f, 0.f);
    if (node0 + node < n)
      v = *(const float4*)&H4[(size_t)(node0 + node) * 64 + kq * 4];
    *(float4*)&Hs[node][kq * 4] = v;
  }
#pragma unroll
  for (int i = 0; i < 2; ++i) {
    int lin = t + i * 256;
    ((float4*)&W2s[0][0])[lin] = ((const float4*)W2f)[lin];
  }
  ((float4*)&W3s[0][0])[t & 255] = ((const float4*)W3)[t & 255];
  if (t < 32) { b2s[t] = b2f[t]; b3s[t] = b3[t]; }
  __syncthreads();

  const int rg = t >> 4, cg = t & 15;
  float acc[4][2] = {{0.f,0.f},{0.f,0.f},{0.f,0.f},{0.f,0.f}};
#pragma unroll 8
  for (int k = 0; k < 64; ++k) {
    float a[4] = {Hs[rg*4+0][k], Hs[rg*4+1][k], Hs[rg*4+2][k], Hs[rg*4+3][k]};
    float w0 = W2s[k][cg*2], w1 = W2s[k][cg*2+1];
#pragma unroll
    for (int i = 0; i < 4; ++i) { acc[i][0] += a[i]*w0; acc[i][1] += a[i]*w1; }
  }
#pragma unroll
  for (int i = 0; i < 4; ++i) {
    Us[rg*4+i][cg*2+0] = fmaxf(acc[i][0] + b2s[cg*2+0], 0.f);
    Us[rg*4+i][cg*2+1] = fmaxf(acc[i][1] + b2s[cg*2+1], 0.f);
  }
  __syncthreads();

  float acc2[4][2] = {{0.f,0.f},{0.f,0.f},{0.f,0.f},{0.f,0.f}};
#pragma unroll
  for (int k = 0; k < 32; ++k) {
    float a[4] = {Us[rg*4+0][k], Us[rg*4+1][k], Us[rg*4+2][k], Us[rg*4+3][k]};
    float w0 = W3s[k][cg*2], w1 = W3s[k][cg*2+1];
#pragma unroll
    for (int i = 0; i < 4; ++i) { acc2[i][0] += a[i]*w0; acc2[i][1] += a[i]*w1; }
  }
  float (*Os)[36] = (float(*)[36])Hs;
#pragma unroll
  for (int i = 0; i < 4; ++i) {
    Os[rg*4+i][cg*2+0] = acc2[i][0] + b3s[cg*2+0];
    Os[rg*4+i][cg*2+1] = acc2[i][1] + b3s[cg*2+1];
  }
  __syncthreads();
#pragma unroll
  for (int i = 0; i < 2; ++i) {
    int lin = t + i * 256;
    int node = lin >> 3, c4 = lin & 7;
    if (node0 + node < n)
      *(float4*)&Out[(size_t)(node0 + node) * 32 + c4 * 4] =
          *(float4*)&Os[node][c4 * 4];
  }
}

// ---------------------------------------------------------------------------
extern "C" void kernel_launch(void* const* d_in, const int* in_sizes, int n_in,
                              void* d_out, int out_size, void* d_ws, size_t ws_size,
                              hipStream_t stream)
{
  const float* X     = (const float*)d_in[0];
  const float* W1    = (const float*)d_in[1];
  const float* b1    = (const float*)d_in[2];
  const float* Wc1   = (const float*)d_in[3];
  const float* bc1   = (const float*)d_in[4];
  const float* Wc2   = (const float*)d_in[5];
  const float* bc2   = (const float*)d_in[6];
  const float* Wc3   = (const float*)d_in[7];
  const float* bc3   = (const float*)d_in[8];
  const float* gamma = (const float*)d_in[9];
  const float* beta  = (const float*)d_in[10];
  const float* W2    = (const float*)d_in[11];
  const float* b2    = (const float*)d_in[12];
  const float* W3    = (const float*)d_in[13];
  const float* b3    = (const float*)d_in[14];
  const int*   ei    = (const int*)d_in[15];

  const int n  = in_sizes[0] / F_IN;
  const int nE = in_sizes[15] / 2;
  const int* src  = ei;
  const int* dstv = ei + nE;

  const int NB = (n + 511) >> 9;          // buckets of 512 nodes
  const int B  = (nE + 8191) >> 13;       // chunks of 8192 edges
  const int NG = NB * B;
  const int nbG = (NG + 255) / 256;

  char* wsb = (char*)d_ws;
  unsigned short* Pa = (unsigned short*)wsb;               // n*64 bf16
  unsigned short* Pb = (unsigned short*)(wsb + (size_t)n * 128); // n*64 bf16
  float* Pc    = (float*)(wsb + (size_t)n * 256);          // n*64 fp32
  float* H4    = (float*)(wsb + (size_t)n * 512);          // n*64 fp32
  float* stats = H4 + (size_t)n * 64;                      // 128
  float* W2f   = stats + 128;                              // 2048
  float* b2f   = W2f + 2048;                               // 32
  int*   offs  = (int*)(b2f + 32);                         // n+1
  int*   G     = offs + n + 1;                             // NG
  int*   W     = G + NG;                                   // NG+1
  int*   bsum  = W + NG + 1;                               // nbG+1
  int*   adj   = bsum + nbG + 1;                           // nE
  int*   EP    = adj + nE;                                 // nE packed ints
  short8* Wt2  = (short8*)(((uintptr_t)(EP + nE) + 15) & ~(uintptr_t)15);

  const int nb  = (n + 63) / 64;

  // W1 -> fragment-linear bf16, then fused lin1+conv1 (H1 never hits HBM)
  wt_kernel<<<32, 256, 0, stream>>>(W1, Wt2);
  l1c1_kernel<<<nb, 256, 0, stream>>>(X, Wt2, b1, Wc1, Pa, n);

  // CSR build (bucketed, packed EP, no cnt array)
  hist_kernel<<<B, 256, 0, stream>>>(dstv, G, stats, nE, B, NB);
  scan1_kernel<<<nbG, 256, 0, stream>>>(G, W, bsum, NG);
  scan2_kernel<<<1, 256, 0, stream>>>(bsum, nbG);
  scatter2_kernel<<<B, 256, 0, stream>>>(src, dstv, W, bsum, EP, nE, B, NB);
  fillc_kernel<<<NB, 256, 0, stream>>>(EP, W, bsum, offs, adj, n, nE, B, NB);

  // conv2: Pb(bf16) = relu(agg(Pa bf16)/deg + bc1) @ Wc2
  gmm_kernel<true><<<nb, 512, 0, stream>>>(Pa, offs, adj, bc1, Wc2, Pb, n);

  // conv3: Pc(fp32) = relu(agg(Pb bf16)/deg + bc2) @ Wc3
  gmm_kernel<false><<<nb, 512, 0, stream>>>(Pb, offs, adj, bc2, Wc3, Pc, n);

  // conv3 epilogue: H4 = relu(agg(Pc fp32)/deg + bc3); batch stats
  gp_kernel<<<nb, 512, 0, stream>>>(Pc, offs, adj, bc3, H4, stats, n);

  // fold batchnorm into W2, then fused lin2+lin3
  fold_kernel<<<1, 256, 0, stream>>>(stats, gamma, beta, W2, b2, W2f, b2f, n);
  final_kernel<<<nb, 256, 0, stream>>>(H4, W2f, b2f, W3, b3, (float*)d_out, n);
}